// Round 1
// baseline (221.863 us; speedup 1.0000x reference)
//
#include <hip/hip_runtime.h>
#include <math.h>
#include <stdint.h>

// Problem constants (B=4, S=4096, D=2048, E=64, K=8)
#define NTOK   16384      // B*S
#define DDIM   2048
#define NE     64
#define TOPK   8

#define THREADS 512
#define TOKPB   32        // tokens per block -> 512 blocks -> 2 resident/CU
#define BK      64        // K-chunk per stage
#define NCHUNK  (DDIM / BK)   // 32

// float4 slots: x tile [32 t][16 k4] (8 KiB), W tile [64 k][16 e4] (16 KiB)
#define XSLOTS   (TOKPB * (BK / 4))   // 512
#define WSLOTS   (BK * (NE / 4))      // 1024
#define BUFSLOTS (XSLOTS + WSLOTS)    // 1536 (24 KiB)
#define NBUF     3                    // 72 KiB total; 2 blocks/CU = 144 KiB <= 160

// Async global->LDS DMA, 16 B per lane. LDS dest is wave-uniform base +
// lane*16 (m104/m108) -- per-lane layout choice happens on the global
// address side (pre-swizzled source, linear dest: rule #21).
__device__ __forceinline__ void gl_lds16(const void* g, void* l) {
    __builtin_amdgcn_global_load_lds(
        (const __attribute__((address_space(1))) void*)(uintptr_t)g,
        (__attribute__((address_space(3))) void*)(uintptr_t)l,
        16, 0, 0);
}

__global__ __launch_bounds__(THREADS, 4) void gate_kernel(
    const float* __restrict__ x, const float* __restrict__ W,
    const float* __restrict__ b, float* __restrict__ out)
{
    __shared__ float4 smem[NBUF * BUFSLOTS];   // 72 KiB

    const int tid  = threadIdx.x;
    const int wave = tid >> 6;
    const int ks   = tid >> 5;        // k-slice 0..15 (4 k each per chunk)
    const int p    = tid & 31;
    const int tg   = p >> 3;          // token group 0..3 (8 tokens each)
    const int eg   = p & 7;           // expert group 0..7 (8 experts each)
    const int tok0 = blockIdx.x * TOKPB;

    // ---- staging sources (per-lane constants) ----
    // x LDS slot s = tid: t = s>>4, kp = s&15; slot holds
    // x[t][4*(kp ^ ((t>>3)&3))] -> read of x[t][4*ks] lands at slot
    // (t, ks ^ tg), spreading the 4 token-groups across bank quads.
    // Source is 16 lanes per token row -> fully coalesced 256 B runs.
    const int st_t  = tid >> 4;       // 0..31
    const int st_kp = tid & 15;
    const float* gx  = x + (size_t)(tok0 + st_t) * DDIM
                         + 4 * (st_kp ^ ((st_t >> 3) & 3));
    // W LDS slot s = j*512 + tid: k = s>>4, ep = s&15; holds
    // W[k][4*(ep ^ ((k>>2)&7))]; (k>>2)&7 == wave for both j -> same XOR.
    const float* gw0 = W + (size_t)st_t        * NE + 4 * (st_kp ^ wave);
    const float* gw1 = W + (size_t)(st_t + 32) * NE + 4 * (st_kp ^ wave);

    auto stage = [&](int c) {
        float4* Bf = &smem[(c % NBUF) * BUFSLOTS];
        const int kc = c * BK;
        gl_lds16(gx + kc,               &Bf[wave * 64]);
        gl_lds16(gw0 + (size_t)kc * NE, &Bf[XSLOTS + wave * 64]);
        gl_lds16(gw1 + (size_t)kc * NE, &Bf[XSLOTS + 512 + wave * 64]);
    };

    float acc[8][8];
#pragma unroll
    for (int i = 0; i < 8; ++i)
#pragma unroll
        for (int j = 0; j < 8; ++j) acc[i][j] = 0.f;

    // Per chunk per thread: 16 ds_read_b128 (8 W + 8 x) feed 256 FMAs.
    // W resident in regs (32 VGPR), x transient (4 VGPR) -> ~118 VGPR total.
    auto compute = [&](int c) {
        const float4* BX = &smem[(c % NBUF) * BUFSLOTS];
        const float4* BW = BX + XSLOTS;
        float4 wreg[4][2];
#pragma unroll
        for (int kk = 0; kk < 4; ++kk) {
            const int k = ks * 4 + kk;
            wreg[kk][0] = BW[k * 16 + ((eg * 2)     ^ (ks & 7))];
            wreg[kk][1] = BW[k * 16 + ((eg * 2 + 1) ^ (ks & 7))];
        }
#pragma unroll
        for (int i = 0; i < 8; ++i) {
            const float4 xv = BX[(tg * 8 + i) * 16 + (ks ^ tg)];
            const float* xp = (const float*)&xv;
#pragma unroll
            for (int kk = 0; kk < 4; ++kk) {
                const float xs = xp[kk];
                const float* w0 = (const float*)&wreg[kk][0];
                const float* w1 = (const float*)&wreg[kk][1];
#pragma unroll
                for (int m = 0; m < 4; ++m) {
                    acc[i][m]     = fmaf(xs, w0[m], acc[i][m]);
                    acc[i][4 + m] = fmaf(xs, w1[m], acc[i][4 + m]);
                }
            }
        }
    };

    // ---- 3-buffer pipeline, counted vmcnt, raw barriers (T3/T4) ----
    // Invariant at the wait of iter c: outstanding DMA  {stage(c), stage(c+1)};
    // vmcnt(3) retires stage(c) (in-order, m135), leaves stage(c+1) in flight.
    // The barrier then makes all waves' stage(c) visible. stage(c+2) is issued
    // AFTER the barrier: every wave has finished reading buf[(c+2)%3] (== the
    // buffer of chunk c-1) before anyone re-stages it -> race-free with a
    // single barrier per chunk.
    stage(0); stage(1);
#pragma unroll 1
    for (int c = 0; c < NCHUNK - 1; ++c) {
        asm volatile("s_waitcnt vmcnt(3)" ::: "memory");
        __builtin_amdgcn_s_barrier();
        if (c + 2 < NCHUNK) stage(c + 2);
        compute(c);
    }
    asm volatile("s_waitcnt vmcnt(0)" ::: "memory");
    __builtin_amdgcn_s_barrier();
    compute(NCHUNK - 1);
    __syncthreads();   // vmcnt already 0; safe to repurpose smem

    // ---- reduce the ks pair (lanes l, l^32 share (tg,eg)) ----
#pragma unroll
    for (int i = 0; i < 8; ++i)
#pragma unroll
        for (int j = 0; j < 8; ++j)
            acc[i][j] += __shfl_xor(acc[i][j], 32);

    // ---- cross-wave partials: [8 w][32 p][68 pad] floats (69.6 KiB) ----
    float* part = (float*)smem;
    if ((tid & 63) < 32) {
        float* dst = part + wave * 2176 + p * 68;
#pragma unroll
        for (int fq = 0; fq < 16; ++fq) {
            const int i = fq >> 1, h = fq & 1;
            *(float4*)(dst + fq * 4) = make_float4(
                acc[i][h * 4], acc[i][h * 4 + 1],
                acc[i][h * 4 + 2], acc[i][h * 4 + 3]);
        }
    }
    __syncthreads();

    // ---- collect 8 wave-partials, add bias, sigmoid ----
    // thread tid -> token t = tid>>4, expert quad e4 = tid&15
    const int t  = tid >> 4;
    const int e4 = tid & 15;
    const int cp = ((t >> 3) << 3) + (e4 >> 1);   // partial p index
    const int cf = ((t & 7) << 1) + (e4 & 1);     // partial f4 index
    const float4* pf4 = (const float4*)part;
    float sx = 0.f, sy = 0.f, sz = 0.f, sw = 0.f;
#pragma unroll
    for (int w = 0; w < 8; ++w) {
        const float4 v = pf4[w * 544 + cp * 17 + cf];
        sx += v.x; sy += v.y; sz += v.z; sw += v.w;
    }
    __syncthreads();   // all partial reads done before score overwrite

    const float4 bv = *(const float4*)(b + e4 * 4);
    float4 sg;
    sg.x = 1.f / (1.f + expf(-(sx + bv.x)));
    sg.y = 1.f / (1.f + expf(-(sy + bv.y)));
    sg.z = 1.f / (1.f + expf(-(sz + bv.z)));
    sg.w = 1.f / (1.f + expf(-(sw + bv.w)));

    float* out_g   = out;                           // [16384][8]
    float* out_idx = out + (size_t)NTOK * TOPK;     // [16384][8] (as float)
    float* out_s   = out + (size_t)NTOK * TOPK * 2; // [16384][64]

    *(float4*)(out_s + (size_t)(tok0 + t) * NE + e4 * 4) = sg;  // coalesced
    float4* sc4 = (float4*)part;                   // scores [32 t][17 f4]
    sc4[t * 17 + e4] = sg;
    __syncthreads();

    // ---- parallel top-8: 8 lanes per token, butterfly argmax with
    // lowest-index tie-break (matches jax.lax.top_k) ----
    if (tid < 256) {
        const int tt = tid >> 3, lg = tid & 7;
        const float4 a0 = sc4[tt * 17 + lg * 2];
        const float4 a1 = sc4[tt * 17 + lg * 2 + 1];
        float s[8] = {a0.x, a0.y, a0.z, a0.w, a1.x, a1.y, a1.z, a1.w};
        float vsel = 0.f; int esel = 0; float ssum = 0.f;
#pragma unroll
        for (int j = 0; j < TOPK; ++j) {
            // local max over remaining 8 (ascending scan, strict > -> lowest idx)
            float bvv = s[0]; int be = 0;
#pragma unroll
            for (int m = 1; m < 8; ++m)
                if (s[m] > bvv) { bvv = s[m]; be = m; }
            float v = bvv; int ec = lg * 8 + be;
#pragma unroll
            for (int d = 1; d < 8; d <<= 1) {
                const float ov = __shfl_xor(v, d);
                const int   oe = __shfl_xor(ec, d);
                if (ov > v || (ov == v && oe < ec)) { v = ov; ec = oe; }
            }
            ssum += v;
            if (lg == j) { vsel = v; esel = ec; }
            // remove winner (static indexing only -- rule #20)
            if ((ec >> 3) == lg) {
                const int sl = ec & 7;
#pragma unroll
                for (int m = 0; m < 8; ++m)
                    if (sl == m) s[m] = -1.f;   // sigmoid in (0,1) -> excluded
            }
        }
        const float inv = 1.f / ssum;
        out_g  [(size_t)(tok0 + tt) * TOPK + lg] = vsel * inv;
        out_idx[(size_t)(tok0 + tt) * TOPK + lg] = (float)esel;
    }
}

extern "C" void kernel_launch(void* const* d_in, const int* in_sizes, int n_in,
                              void* d_out, int out_size, void* d_ws, size_t ws_size,
                              hipStream_t stream) {
    const float* x = (const float*)d_in[0];
    const float* W = (const float*)d_in[1];
    const float* b = (const float*)d_in[2];
    // d_in[3] is k (==8), compile-time constant here.
    float* out = (float*)d_out;
    gate_kernel<<<NTOK / TOKPB, THREADS, 0, stream>>>(x, W, b, out);
}